// Round 5
// baseline (187.664 us; speedup 1.0000x reference)
//
#include <hip/hip_runtime.h>
#include <stdint.h>

typedef __attribute__((ext_vector_type(4))) float float4v;

#define D 4096
#define R 16
#define NW 192     // adapters
#define LB 1280    // lora rows
#define NBL 256
#define MAXB 32    // max bucket size (actual max ~16-17, binomial(1280,1/192))
#define NWAVE 16   // waves per block

// ---------------- fused: per-adapter A->h->B->atomic-out ----------------
// Round-4 post-mortem: fused kernel is 48us with no pipe >21% busy, but
// end-to-end minus fused is a CONSTANT ~100us across 4 structurally
// different rounds -> the dispatch sequence itself (2nd kernel + ybuf
// round-trip + per-dispatch overhead) is now the dominant cost.
// This round: kill the ybuf round-trip and the sum4 launch. Large-segment
// rows unsafeAtomicAdd (hw global_atomic_add_f32) straight into out[b>>2];
// small rows keep unique-writer plain stores. out zeroed via stream-ordered
// hipMemsetAsync. Saves 40MB of ybuf traffic + one launch; contention is
// <=4 adds per output element, fp32 reorder noise << passing tolerance.
// Fused body otherwise identical to round-4 (proven 48us, VGPR=56 no spill):
//  - coalesced LDS-staged x (1 dwordx4/lane/row), 2-deep row pipeline
//  - A tile in registers, B loads hoisted over the hws barrier
__global__ __launch_bounds__(1024, 4) void fused_kernel(
    const float* __restrict__ x,
    const float* __restrict__ A,
    const float* __restrict__ B,
    const int* __restrict__ xids,
    const int* __restrict__ wids,
    float* __restrict__ out)    // [512][D], pre-zeroed
{
    const int w = blockIdx.x;
    const int t = threadIdx.x;
    const int lane = t & 63;
    const int wave = t >> 6;

    __shared__ int list[MAXB];
    __shared__ int xidl[MAXB];
    __shared__ int cnt;
    __shared__ float hws[MAXB][NWAVE][17];  // +1 pad: stride 17 kills bank conflicts
    __shared__ float hl[MAXB][R];
    __shared__ float xs[2][NWAVE][256];     // double-buffered per-wave x slices

    if (t == 0) cnt = 0;
    __syncthreads();
    for (int i = t; i < LB; i += 1024)
        if (wids[i] == w) { int q = atomicAdd(&cnt, 1); if (q < MAXB) list[q] = i; }
    __syncthreads();
    int n = cnt > MAXB ? MAXB : cnt;
    if (n == 0) return;
    if (t < n) xidl[t] = xids[list[t]];
    __syncthreads();

    // lane owns d = 256*wave + (lane>>2) + 16k (k=0..15), r = 4*(lane&3)+c.
    const int xcol = 256 * wave + 4 * lane;   // coalesced slice col for staging

    // issue row-0 x load first so it's in flight under the A burst
    float4v xv0 = *(const float4v*)(x + (size_t)xidl[0] * D + xcol);

    const float4v* af = (const float4v*)(A + (size_t)w * D * R);
    float4v a[16];
    #pragma unroll
    for (int k = 0; k < 16; ++k) a[k] = af[1024 * wave + 64 * k + lane];

#define ROW_COMPUTE(i, buf)                                               \
    { float h0 = 0.f, h1 = 0.f, h2 = 0.f, h3 = 0.f;                       \
      _Pragma("unroll")                                                   \
      for (int k = 0; k < 16; ++k) {                                      \
          const float xd = xs[buf][wave][(lane >> 2) + 16 * k];           \
          h0 += xd * a[k][0]; h1 += xd * a[k][1];                         \
          h2 += xd * a[k][2]; h3 += xd * a[k][3];                         \
      }                                                                   \
      _Pragma("unroll")                                                   \
      for (int off = 4; off <= 32; off <<= 1) {                           \
          h0 += __shfl_xor(h0, off, 64); h1 += __shfl_xor(h1, off, 64);   \
          h2 += __shfl_xor(h2, off, 64); h3 += __shfl_xor(h3, off, 64);   \
      }                                                                   \
      if (lane < 4) {                                                     \
          hws[i][wave][4 * lane + 0] = h0;                                \
          hws[i][wave][4 * lane + 1] = h1;                                \
          hws[i][wave][4 * lane + 2] = h2;                                \
          hws[i][wave][4 * lane + 3] = h3;                                \
      } }

    // ---- phase 1: h[i][r] = x[xid_i] . A, 2-deep pipelined, LDS-staged ----
    float4v xv1;
    *(float4v*)(&xs[0][wave][4 * lane]) = xv0;
    for (int i = 0; i < n; i += 2) {
        if (i + 1 < n)
            xv1 = *(const float4v*)(x + (size_t)xidl[i + 1] * D + xcol);
        ROW_COMPUTE(i, 0);
        if (i + 1 < n) {
            *(float4v*)(&xs[1][wave][4 * lane]) = xv1;
            if (i + 2 < n)
                xv0 = *(const float4v*)(x + (size_t)xidl[i + 2] * D + xcol);
            ROW_COMPUTE(i + 1, 1);
            if (i + 2 < n)
                *(float4v*)(&xs[0][wave][4 * lane]) = xv0;
        }
    }
#undef ROW_COMPUTE

    // B loads issued before the barrier: fetch overlaps hl-combine; a[] is
    // dead here so the allocator reuses its registers.
    const float* Bw = B + (size_t)w * R * D + 4 * t;
    float4v breg[R];
    #pragma unroll
    for (int r = 0; r < R; ++r) breg[r] = *(const float4v*)(Bw + (size_t)r * D);

    __syncthreads();
    for (int idx = t; idx < n * R; idx += 1024) {
        const int i = idx >> 4, r = idx & 15;
        float sacc = 0.f;
        #pragma unroll
        for (int j = 0; j < NWAVE; ++j) sacc += hws[i][j][r];
        hl[i][r] = sacc;
    }
    __syncthreads();

    // ---- phase 2: y = 2*h.B, accumulated straight into out ----
    for (int i = 0; i < n; ++i) {
        const int b = list[i];
        float4v acc = {0.f, 0.f, 0.f, 0.f};
        #pragma unroll
        for (int r = 0; r < R; ++r) {
            const float hr = hl[i][r];         // LDS broadcast
            acc[0] += hr * breg[r][0];
            acc[1] += hr * breg[r][1];
            acc[2] += hr * breg[r][2];
            acc[3] += hr * breg[r][3];
        }
        #pragma unroll
        for (int k = 0; k < 4; ++k) acc[k] *= 2.0f;

        if (b < NBL * 4) {
            // segment-sum: <=4 contributors per element, hw f32 atomic
            float* op = out + (size_t)(b >> 2) * D + 4 * t;
            unsafeAtomicAdd(op + 0, acc[0]);
            unsafeAtomicAdd(op + 1, acc[1]);
            unsafeAtomicAdd(op + 2, acc[2]);
            unsafeAtomicAdd(op + 3, acc[3]);
        } else {
            // small rows: unique writer, plain store
            *(float4v*)(out + (size_t)(NBL + (b - NBL * 4)) * D + 4 * t) = acc;
        }
    }
}

extern "C" void kernel_launch(void* const* d_in, const int* in_sizes, int n_in,
                              void* d_out, int out_size, void* d_ws, size_t ws_size,
                              hipStream_t stream) {
    const float* x    = (const float*)d_in[0];
    const float* A    = (const float*)d_in[1];
    const float* B    = (const float*)d_in[2];
    const int*   xids = (const int*)d_in[3];
    const int*   wids = (const int*)d_in[4];
    float*       out  = (float*)d_out;

    // out pre-zeroed (stream-ordered, graph-capturable); atomics accumulate.
    hipMemsetAsync(d_out, 0, (size_t)out_size, stream);
    hipLaunchKernelGGL(fused_kernel, dim3(NW), dim3(1024), 0, stream,
                       x, A, B, xids, wids, out);
}

// Round 6
// 159.094 us; speedup vs baseline: 1.1796x; 1.1796x over previous
//
#include <hip/hip_runtime.h>
#include <stdint.h>

typedef __attribute__((ext_vector_type(4))) float float4v;

#define D 4096
#define R 16
#define NW 192     // adapters
#define LB 1280    // lora rows
#define NBL 256
#define MAXB 32    // max bucket size (actual max ~16-17, binomial(1280,1/192))
#define NWAVE 16   // waves per block

// ---------------- fused: per-adapter A->h->B->y ----------------
// Round-5 post-mortem: global f32 atomics tripled write traffic (WRITE_SIZE
// 20->70MB, fused 48->88us) -- cross-XCD RMW can't write-combine. Reverted to
// the proven ybuf+sum4 reduction (round 4, 149.4us end-to-end).
// Fixed-cost finding: end-to-end minus fused GPU time is ~100us across ALL
// structures (2 kernels, 1 kernel+memset) -> harness reset cost, untouchable.
// Only the ~52us of GPU time is in play.
// Standing theory: per-block time = sequential fetch BURSTS (A 256KB ->
// compute -> B 256KB), phase-synchronized across all 192 blocks, memory
// system alternating saturated/idle. Round 3 proved A+B fully in regs spills
// (~160 VGPR > 128 cap @1024thr). This round: prefetch HALF of B (rows 0-7,
// 32 VGPR) before phase 1 -- est ~115 live VGPR < 128, no spill -- hiding
// half the B-burst under phase-1 compute. Rows 8-15 load at round-4's spot
// (overlapping the hl-combine).
// Spill check in counters: WRITE_SIZE == 20480KB exactly, VGPR ~100-125.
__global__ __launch_bounds__(1024, 4) void fused_kernel(
    const float* __restrict__ x,
    const float* __restrict__ A,
    const float* __restrict__ B,
    const int* __restrict__ xids,
    const int* __restrict__ wids,
    float* __restrict__ ybuf,   // [NBL*4][D]
    float* __restrict__ out)    // [512][D]
{
    const int w = blockIdx.x;
    const int t = threadIdx.x;
    const int lane = t & 63;
    const int wave = t >> 6;

    __shared__ int list[MAXB];
    __shared__ int xidl[MAXB];
    __shared__ int cnt;
    __shared__ float hws[MAXB][NWAVE][17];  // +1 pad: stride 17 kills bank conflicts
    __shared__ float hl[MAXB][R];
    __shared__ float xs[2][NWAVE][256];     // double-buffered per-wave x slices

    if (t == 0) cnt = 0;
    __syncthreads();
    for (int i = t; i < LB; i += 1024)
        if (wids[i] == w) { int q = atomicAdd(&cnt, 1); if (q < MAXB) list[q] = i; }
    __syncthreads();
    int n = cnt > MAXB ? MAXB : cnt;
    if (n == 0) return;
    if (t < n) xidl[t] = xids[list[t]];
    __syncthreads();

    // lane owns d = 256*wave + (lane>>2) + 16k (k=0..15), r = 4*(lane&3)+c.
    const int xcol = 256 * wave + 4 * lane;   // coalesced slice col for staging

    // issue row-0 x load first so it's in flight under the A burst
    float4v xv0 = *(const float4v*)(x + (size_t)xidl[0] * D + xcol);

    const float4v* af = (const float4v*)(A + (size_t)w * D * R);
    float4v a[16];
    #pragma unroll
    for (int k = 0; k < 16; ++k) a[k] = af[1024 * wave + 64 * k + lane];

    // ---- B rows 0-7 prefetched BEFORE phase 1 (32 VGPR, fits budget) ----
    // Their fetch latency hides under the entire phase-1 row loop.
    const float* Bw = B + (size_t)w * R * D + 4 * t;
    float4v breg_lo[8];
    #pragma unroll
    for (int r = 0; r < 8; ++r) breg_lo[r] = *(const float4v*)(Bw + (size_t)r * D);

#define ROW_COMPUTE(i, buf)                                               \
    { float h0 = 0.f, h1 = 0.f, h2 = 0.f, h3 = 0.f;                       \
      _Pragma("unroll")                                                   \
      for (int k = 0; k < 16; ++k) {                                      \
          const float xd = xs[buf][wave][(lane >> 2) + 16 * k];           \
          h0 += xd * a[k][0]; h1 += xd * a[k][1];                         \
          h2 += xd * a[k][2]; h3 += xd * a[k][3];                         \
      }                                                                   \
      _Pragma("unroll")                                                   \
      for (int off = 4; off <= 32; off <<= 1) {                           \
          h0 += __shfl_xor(h0, off, 64); h1 += __shfl_xor(h1, off, 64);   \
          h2 += __shfl_xor(h2, off, 64); h3 += __shfl_xor(h3, off, 64);   \
      }                                                                   \
      if (lane < 4) {                                                     \
          hws[i][wave][4 * lane + 0] = h0;                                \
          hws[i][wave][4 * lane + 1] = h1;                                \
          hws[i][wave][4 * lane + 2] = h2;                                \
          hws[i][wave][4 * lane + 3] = h3;                                \
      } }

    // ---- phase 1: h[i][r] = x[xid_i] . A, 2-deep pipelined, LDS-staged ----
    float4v xv1;
    *(float4v*)(&xs[0][wave][4 * lane]) = xv0;
    for (int i = 0; i < n; i += 2) {
        if (i + 1 < n)
            xv1 = *(const float4v*)(x + (size_t)xidl[i + 1] * D + xcol);
        ROW_COMPUTE(i, 0);
        if (i + 1 < n) {
            *(float4v*)(&xs[1][wave][4 * lane]) = xv1;
            if (i + 2 < n)
                xv0 = *(const float4v*)(x + (size_t)xidl[i + 2] * D + xcol);
            ROW_COMPUTE(i + 1, 1);
            if (i + 2 < n)
                *(float4v*)(&xs[0][wave][4 * lane]) = xv0;
        }
    }
#undef ROW_COMPUTE

    // B rows 8-15 issued before the barrier: fetch overlaps the hl-combine;
    // a[] is dead here so the allocator reuses its registers.
    float4v breg_hi[8];
    #pragma unroll
    for (int r = 0; r < 8; ++r) breg_hi[r] = *(const float4v*)(Bw + (size_t)(r + 8) * D);

    __syncthreads();
    for (int idx = t; idx < n * R; idx += 1024) {
        const int i = idx >> 4, r = idx & 15;
        float sacc = 0.f;
        #pragma unroll
        for (int j = 0; j < NWAVE; ++j) sacc += hws[i][j][r];
        hl[i][r] = sacc;
    }
    __syncthreads();

    // ---- phase 2: y = 2*h.B ----
    for (int i = 0; i < n; ++i) {
        const int b = list[i];
        float4v acc = {0.f, 0.f, 0.f, 0.f};
        #pragma unroll
        for (int r = 0; r < 8; ++r) {
            const float hr = hl[i][r];         // LDS broadcast
            acc[0] += hr * breg_lo[r][0];
            acc[1] += hr * breg_lo[r][1];
            acc[2] += hr * breg_lo[r][2];
            acc[3] += hr * breg_lo[r][3];
        }
        #pragma unroll
        for (int r = 0; r < 8; ++r) {
            const float hr = hl[i][r + 8];     // LDS broadcast
            acc[0] += hr * breg_hi[r][0];
            acc[1] += hr * breg_hi[r][1];
            acc[2] += hr * breg_hi[r][2];
            acc[3] += hr * breg_hi[r][3];
        }
        #pragma unroll
        for (int k = 0; k < 4; ++k) acc[k] *= 2.0f;

        if (b < NBL * 4) {
            *(float4v*)(ybuf + (size_t)b * D + 4 * t) = acc;        // unique writer
        } else {
            *(float4v*)(out + (size_t)(NBL + (b - NBL * 4)) * D + 4 * t) = acc;
        }
    }
}

// ---------------- sum4: out[o] = ybuf[4o]+ybuf[4o+1]+ybuf[4o+2]+ybuf[4o+3] ---
__global__ __launch_bounds__(256) void sum4_kernel(
    const float* __restrict__ ybuf,
    float* __restrict__ out)
{
    const int o = blockIdx.x >> 2;            // 0..255
    const int q = blockIdx.x & 3;             // d-quarter
    const int col = q * 1024 + 4 * threadIdx.x;
    const float* y0 = ybuf + (size_t)(4 * o) * D + col;
    float4v v0 = *(const float4v*)(y0);
    float4v v1 = *(const float4v*)(y0 + D);
    float4v v2 = *(const float4v*)(y0 + 2 * D);
    float4v v3 = *(const float4v*)(y0 + 3 * D);
    float4v s;
    #pragma unroll
    for (int k = 0; k < 4; ++k) s[k] = (v0[k] + v1[k]) + (v2[k] + v3[k]);
    *(float4v*)(out + (size_t)o * D + col) = s;
}

extern "C" void kernel_launch(void* const* d_in, const int* in_sizes, int n_in,
                              void* d_out, int out_size, void* d_ws, size_t ws_size,
                              hipStream_t stream) {
    const float* x    = (const float*)d_in[0];
    const float* A    = (const float*)d_in[1];
    const float* B    = (const float*)d_in[2];
    const int*   xids = (const int*)d_in[3];
    const int*   wids = (const int*)d_in[4];
    float*       out  = (float*)d_out;

    float* ybuf = (float*)d_ws;   // [1024][4096] f32 = 16 MB

    hipLaunchKernelGGL(fused_kernel, dim3(NW), dim3(1024), 0, stream,
                       x, A, B, xids, wids, ybuf, out);
    hipLaunchKernelGGL(sum4_kernel, dim3(NBL * 4), dim3(256), 0, stream,
                       ybuf, out);
}

// Round 8
// 153.126 us; speedup vs baseline: 1.2256x; 1.0390x over previous
//
#include <hip/hip_runtime.h>
#include <stdint.h>

typedef __attribute__((ext_vector_type(4))) float float4v;

#define D 4096
#define R 16
#define NW 192     // adapters
#define LB 1280    // lora rows
#define NBL 256
#define MAXB 32    // max bucket size (actual max ~16-17, binomial(1280,1/192))
#define NWAVE 16   // waves per block
#define NLDSB 6    // B rows staged in LDS via global_load_lds (96 KB)

// ---------------- fused: per-adapter A->h->B->y ----------------
// r6 post-mortem: register-held B prefetch spilled (VGPR=64, WRITE_SIZE
// 20->35MB): at LDS=70KB two blocks fit per CU, so the allocator targets 64
// VGPR for co-residency and spills the rest. r7 (this design) hit a container
// failure -- resubmitted with exotic surface trimmed (no main-path inline-asm
// waitcnt / sched_barrier; the __syncthreads before hl-combine drains vmcnt,
// the proven m97 pattern).
// Design: start B's fetch at t=0 with ZERO register cost:
//  - B rows 0..5 (96KB) DMA'd global->LDS via __builtin_amdgcn_global_load_lds,
//    issued as the FIRST instructions (address needs only blockIdx). Fetch
//    overlaps wids-scan + A-burst + all of phase 1.
//  - wave v DMAs bytes [1024v,1024v+1024) of each row; thread t later reads
//    bytes 16t -- inside its own wave's segment; the pre-read __syncthreads
//    (compiler drains vmcnt(0) at barriers) fences the DMA.
//  - B rows 6..15 in the r4-proven register slot (loaded after phase 1 where
//    a[] is dead; that slot never spilled).
//  - LDS ~148KB -> 1 block/CU -> removes the 64-VGPR/2-block allocator
//    incentive that caused the r3/r6 spills.
//  - xs single-buffered (wave-private; DS ops within a wave are in-order and
//    the compiler can't reorder aliasing LDS accesses) to fit LDS.
// Spill check in counters: WRITE_SIZE == 20480KB exactly.
__global__ __launch_bounds__(1024, 4) void fused_kernel(
    const float* __restrict__ x,
    const float* __restrict__ A,
    const float* __restrict__ B,
    const int* __restrict__ xids,
    const int* __restrict__ wids,
    float* __restrict__ ybuf,   // [NBL*4][D]
    float* __restrict__ out)    // [512][D]
{
    const int w = blockIdx.x;
    const int t = threadIdx.x;
    const int lane = t & 63;
    const int wave = t >> 6;

    __shared__ float ldsB[NLDSB][D];        // 96 KB, filled by async DMA
    __shared__ int list[MAXB];
    __shared__ int xidl[MAXB];
    __shared__ int cnt;
    __shared__ float hws[MAXB][NWAVE][17];  // +1 pad: stride 17 kills bank conflicts
    __shared__ float hl[MAXB][R];
    __shared__ float xs[NWAVE][256];        // single-buffer per-wave x slice

    // ---- issue B rows 0..5 into LDS immediately (async, zero VGPR) ----
    // gsrc per-lane (+lane*16B); LDS dest is wave-uniform base, HW adds
    // lane*16B. Width 16 must be a literal.
    {
        const float* Bb = B + (size_t)w * R * D + (wave << 8) + (lane << 2);
        #pragma unroll
        for (int r = 0; r < NLDSB; ++r)
            __builtin_amdgcn_global_load_lds(
                (const __attribute__((address_space(1))) uint32_t*)(Bb + (size_t)r * D),
                (__attribute__((address_space(3))) uint32_t*)(&ldsB[r][wave << 8]),
                16, 0, 0);
    }

    if (t == 0) cnt = 0;
    __syncthreads();
    for (int i = t; i < LB; i += 1024)
        if (wids[i] == w) { int q = atomicAdd(&cnt, 1); if (q < MAXB) list[q] = i; }
    __syncthreads();
    int n = cnt > MAXB ? MAXB : cnt;
    if (n == 0) {
        // drain our wave's DMA before LDS dealloc (stray writes could land
        // in a successor block's freshly-allocated LDS)
        asm volatile("s_waitcnt vmcnt(0)" ::: "memory");
        return;
    }
    if (t < n) xidl[t] = xids[list[t]];
    __syncthreads();

    // lane owns d = 256*wave + (lane>>2) + 16k (k=0..15), r = 4*(lane&3)+c.
    const int xcol = (wave << 8) + (lane << 2);   // coalesced staging col

    // issue row-0 x load first so it's in flight under the A burst
    float4v xv = *(const float4v*)(x + (size_t)xidl[0] * D + xcol);

    const float4v* af = (const float4v*)(A + (size_t)w * D * R);
    float4v a[16];
    #pragma unroll
    for (int k = 0; k < 16; ++k) a[k] = af[1024 * wave + 64 * k + lane];

#define ROW_COMPUTE(i)                                                    \
    { float h0 = 0.f, h1 = 0.f, h2 = 0.f, h3 = 0.f;                       \
      _Pragma("unroll")                                                   \
      for (int k = 0; k < 16; ++k) {                                      \
          const float xd = xs[wave][(lane >> 2) + 16 * k];                \
          h0 += xd * a[k][0]; h1 += xd * a[k][1];                         \
          h2 += xd * a[k][2]; h3 += xd * a[k][3];                         \
      }                                                                   \
      _Pragma("unroll")                                                   \
      for (int off = 4; off <= 32; off <<= 1) {                           \
          h0 += __shfl_xor(h0, off, 64); h1 += __shfl_xor(h1, off, 64);   \
          h2 += __shfl_xor(h2, off, 64); h3 += __shfl_xor(h3, off, 64);   \
      }                                                                   \
      if (lane < 4) {                                                     \
          hws[i][wave][4 * lane + 0] = h0;                                \
          hws[i][wave][4 * lane + 1] = h1;                                \
          hws[i][wave][4 * lane + 2] = h2;                                \
          hws[i][wave][4 * lane + 3] = h3;                                \
      } }

    // ---- phase 1: h[i][r] = x[xid_i] . A, pipelined, LDS-staged ----
    // xs is wave-private; DS ops within a wave are in-order and the accesses
    // alias, so the single buffer is safe without syncs.
    *(float4v*)(&xs[wave][lane << 2]) = xv;
    for (int i = 0; i < n; ++i) {
        float4v xvn;
        if (i + 1 < n)
            xvn = *(const float4v*)(x + (size_t)xidl[i + 1] * D + xcol);
        ROW_COMPUTE(i);
        if (i + 1 < n)
            *(float4v*)(&xs[wave][lane << 2]) = xvn;
    }
#undef ROW_COMPUTE

    // B rows 6..15 issued in the r4-proven slot: a[] is dead, allocator
    // reuses its registers; fetch starts here, completes across the barrier.
    const float* Bw = B + (size_t)w * R * D + 4 * t;
    float4v breg_hi[R - NLDSB];
    #pragma unroll
    for (int r = 0; r < R - NLDSB; ++r)
        breg_hi[r] = *(const float4v*)(Bw + (size_t)(r + NLDSB) * D);

    // barrier drains vmcnt(0): fences both the B-DMA into ldsB and breg_hi
    __syncthreads();
    for (int idx = t; idx < n * R; idx += 1024) {
        const int i = idx >> 4, r = idx & 15;
        float sacc = 0.f;
        #pragma unroll
        for (int j = 0; j < NWAVE; ++j) sacc += hws[i][j][r];
        hl[i][r] = sacc;
    }
    __syncthreads();

    // ---- phase 2: y = 2*h.B ----
    // hoist the 6 LDS-resident B rows into registers once (loop-invariant).
    float4v bl[NLDSB];
    #pragma unroll
    for (int r = 0; r < NLDSB; ++r)
        bl[r] = *(const float4v*)(&ldsB[r][t << 2]);

    for (int i = 0; i < n; ++i) {
        const int b = list[i];
        float4v acc = {0.f, 0.f, 0.f, 0.f};
        #pragma unroll
        for (int r = 0; r < NLDSB; ++r) {
            const float hr = hl[i][r];         // LDS broadcast
            acc[0] += hr * bl[r][0];
            acc[1] += hr * bl[r][1];
            acc[2] += hr * bl[r][2];
            acc[3] += hr * bl[r][3];
        }
        #pragma unroll
        for (int r = 0; r < R - NLDSB; ++r) {
            const float hr = hl[i][r + NLDSB]; // LDS broadcast
            acc[0] += hr * breg_hi[r][0];
            acc[1] += hr * breg_hi[r][1];
            acc[2] += hr * breg_hi[r][2];
            acc[3] += hr * breg_hi[r][3];
        }
        #pragma unroll
        for (int k = 0; k < 4; ++k) acc[k] *= 2.0f;

        if (b < NBL * 4) {
            *(float4v*)(ybuf + (size_t)b * D + 4 * t) = acc;        // unique writer
        } else {
            *(float4v*)(out + (size_t)(NBL + (b - NBL * 4)) * D + 4 * t) = acc;
        }
    }
}

// ---------------- sum4: out[o] = ybuf[4o]+ybuf[4o+1]+ybuf[4o+2]+ybuf[4o+3] ---
__global__ __launch_bounds__(256) void sum4_kernel(
    const float* __restrict__ ybuf,
    float* __restrict__ out)
{
    const int o = blockIdx.x >> 2;            // 0..255
    const int q = blockIdx.x & 3;             // d-quarter
    const int col = q * 1024 + 4 * threadIdx.x;
    const float* y0 = ybuf + (size_t)(4 * o) * D + col;
    float4v v0 = *(const float4v*)(y0);
    float4v v1 = *(const float4v*)(y0 + D);
    float4v v2 = *(const float4v*)(y0 + 2 * D);
    float4v v3 = *(const float4v*)(y0 + 3 * D);
    float4v s;
    #pragma unroll
    for (int k = 0; k < 4; ++k) s[k] = (v0[k] + v1[k]) + (v2[k] + v3[k]);
    *(float4v*)(out + (size_t)o * D + col) = s;
}

extern "C" void kernel_launch(void* const* d_in, const int* in_sizes, int n_in,
                              void* d_out, int out_size, void* d_ws, size_t ws_size,
                              hipStream_t stream) {
    const float* x    = (const float*)d_in[0];
    const float* A    = (const float*)d_in[1];
    const float* B    = (const float*)d_in[2];
    const int*   xids = (const int*)d_in[3];
    const int*   wids = (const int*)d_in[4];
    float*       out  = (float*)d_out;

    float* ybuf = (float*)d_ws;   // [1024][4096] f32 = 16 MB

    hipLaunchKernelGGL(fused_kernel, dim3(NW), dim3(1024), 0, stream,
                       x, A, B, xids, wids, ybuf, out);
    hipLaunchKernelGGL(sum4_kernel, dim3(NBL * 4), dim3(256), 0, stream,
                       ybuf, out);
}

// Round 9
// 152.593 us; speedup vs baseline: 1.2298x; 1.0035x over previous
//
#include <hip/hip_runtime.h>
#include <stdint.h>

typedef __attribute__((ext_vector_type(4))) float float4v;

#define D 4096
#define R 16
#define NW 192     // adapters
#define LB 1280    // lora rows
#define NBL 256
#define MAXB 32    // max bucket size (actual max ~16-17, binomial(1280,1/192))

// ---- round-9 restructure: two streaming passes instead of one fat kernel ---
// r8 post-mortem: zero-VGPR B-DMA overlap landed cleanly (no spill, WRITE
// exact) and changed NOTHING (48-52us, = r4). Third null overlap experiment.
// With VALUBusy 7% (~3.5us work), HBM 20% (~12us traffic) and occupancy 20%,
// the fat 16-wave 2-phase 5-barrier block has ~35us of structural dead time
// that intra-block scheduling cannot remove.
// New structure: the problem factors into two independent STREAMING passes
// via a tiny intermediate h[1280][16] (80KB):
//   K1 (h = x.A):   768 blocks (adapter w x d-chunk c), streams A once.
//   K2 (y = 2h.B):  768 blocks (adapter w x d-chunk c), streams B once.
//   K3 (sum4):      segment-sum of ybuf.
// 256-thread blocks, ~13KB LDS, ~80 VGPR -> 3 blocks/CU co-resident, no
// cross-phase barrier convoys, and the small block raises the per-thread
// VGPR budget (the 64-VGPR/2-block allocator trap of r3/r6 is gone).
// hpart[4][1280][16] (327KB) lives in out rows 0..79: written by K1,
// read by K2 (which writes only out rows 256+), overwritten by K3 (rows
// 0..255) strictly afterwards. No extra workspace.

// ---------------- K1: hpart[c][row][r] = x[row-chunk c] . A[chunk c] -------
__global__ __launch_bounds__(256) void h_kernel(
    const float* __restrict__ x,
    const float* __restrict__ A,
    const int* __restrict__ xids,
    const int* __restrict__ wids,
    float* __restrict__ hp)     // [4][1280][16], aliased into out rows 0..79
{
    const int w = blockIdx.x >> 2;     // adapter
    const int c = blockIdx.x & 3;      // d-chunk (1024 cols)
    const int t = threadIdx.x;
    const int lane = t & 63;
    const int wv = t >> 6;             // 4 waves

    __shared__ int list[MAXB];
    __shared__ int xidl[MAXB];
    __shared__ int cnt;
    __shared__ float hws[MAXB][4][17];   // +1 pad kills bank conflicts
    __shared__ float xs[4][256];         // per-wave x slice

    if (t == 0) cnt = 0;
    __syncthreads();
    for (int i = t; i < LB; i += 256)
        if (wids[i] == w) { int q = atomicAdd(&cnt, 1); if (q < MAXB) list[q] = i; }
    __syncthreads();
    const int n = cnt > MAXB ? MAXB : cnt;
    if (n == 0) return;
    if (t < n) xidl[t] = xids[list[t]];
    __syncthreads();

    // wave v owns d_local = 256v + (lane>>2) + 16k, r-quad j = lane&3
    // (identical per-wave pattern to the r4-proven kernel, 1/4 the d-range)
    const int xoff = 1024 * c + 256 * wv + 4 * lane;   // coalesced 1KB/wave

    // row-0 x load in flight under the A burst
    float4v xv = *(const float4v*)(x + (size_t)xidl[0] * D + xoff);

    const float4v* af = (const float4v*)(A + ((size_t)w * D + 1024 * c) * R);
    float4v a[16];
    #pragma unroll
    for (int k = 0; k < 16; ++k) a[k] = af[1024 * wv + 64 * k + lane];

    // phase: pipelined rows; xs is wave-private (in-order DS) -> no syncs
    *(float4v*)(&xs[wv][4 * lane]) = xv;
    for (int i = 0; i < n; ++i) {
        float4v xvn;
        if (i + 1 < n)
            xvn = *(const float4v*)(x + (size_t)xidl[i + 1] * D + xoff);
        float h0 = 0.f, h1 = 0.f, h2 = 0.f, h3 = 0.f;
        #pragma unroll
        for (int k = 0; k < 16; ++k) {
            const float xd = xs[wv][(lane >> 2) + 16 * k];   // 4-lane broadcast
            h0 += xd * a[k][0]; h1 += xd * a[k][1];
            h2 += xd * a[k][2]; h3 += xd * a[k][3];
        }
        #pragma unroll
        for (int off = 4; off <= 32; off <<= 1) {
            h0 += __shfl_xor(h0, off, 64); h1 += __shfl_xor(h1, off, 64);
            h2 += __shfl_xor(h2, off, 64); h3 += __shfl_xor(h3, off, 64);
        }
        if (lane < 4) {                  // lane L holds r = 4L..4L+3
            hws[i][wv][4 * lane + 0] = h0;
            hws[i][wv][4 * lane + 1] = h1;
            hws[i][wv][4 * lane + 2] = h2;
            hws[i][wv][4 * lane + 3] = h3;
        }
        if (i + 1 < n)
            *(float4v*)(&xs[wv][4 * lane]) = xvn;
    }
    __syncthreads();

    // combine 4 waves -> hpart (unique writer per (c,row,r))
    for (int idx = t; idx < n * R; idx += 256) {
        const int i = idx >> 4, r = idx & 15;
        const float s = hws[i][0][r] + hws[i][1][r] + hws[i][2][r] + hws[i][3][r];
        hp[((size_t)c * LB + list[i]) * R + r] = s;
    }
}

// ---------------- K2: y[row][chunk c] = 2 * h[row] . B[w][: , chunk c] -----
__global__ __launch_bounds__(256) void y_kernel(
    const float* __restrict__ B,
    const int* __restrict__ wids,
    float* __restrict__ ybuf,   // [NBL*4][D]
    float* out)                 // rows 0..79 = hpart (read), rows 256+ written
{
    const int w = blockIdx.x >> 2;     // adapter
    const int cq = blockIdx.x & 3;     // d-chunk
    const int t = threadIdx.x;

    __shared__ int list[MAXB];
    __shared__ int cnt;
    __shared__ float hl[MAXB][R];

    if (t == 0) cnt = 0;
    __syncthreads();
    for (int i = t; i < LB; i += 256)
        if (wids[i] == w) { int q = atomicAdd(&cnt, 1); if (q < MAXB) list[q] = i; }
    __syncthreads();
    const int n = cnt > MAXB ? MAXB : cnt;
    if (n == 0) return;
    __syncthreads();

    const int col = 1024 * cq + 4 * t;
    const float* Bw = B + (size_t)w * R * D + col;
    float4v breg[R];
    #pragma unroll
    for (int r = 0; r < R; ++r) breg[r] = *(const float4v*)(Bw + (size_t)r * D);

    // h combine: sum the 4 d-chunk partials (tiny, L2-resident)
    const float* hp = out;             // hpart alias, rows 0..79 of out
    for (int idx = t; idx < n * R; idx += 256) {
        const int i = idx >> 4, r = idx & 15;
        const size_t base = (size_t)list[i] * R + r;
        hl[i][r] = hp[base] + hp[(size_t)LB * R + base]
                 + hp[2 * (size_t)LB * R + base] + hp[3 * (size_t)LB * R + base];
    }
    __syncthreads();

    for (int i = 0; i < n; ++i) {
        const int b = list[i];
        float4v acc = {0.f, 0.f, 0.f, 0.f};
        #pragma unroll
        for (int r = 0; r < R; ++r) {
            const float hr = hl[i][r];          // LDS broadcast
            acc[0] += hr * breg[r][0];
            acc[1] += hr * breg[r][1];
            acc[2] += hr * breg[r][2];
            acc[3] += hr * breg[r][3];
        }
        #pragma unroll
        for (int k = 0; k < 4; ++k) acc[k] *= 2.0f;

        if (b < NBL * 4) {
            *(float4v*)(ybuf + (size_t)b * D + col) = acc;           // unique writer
        } else {
            *(float4v*)(out + (size_t)(NBL + (b - NBL * 4)) * D + col) = acc;
        }
    }
}

// ---------------- K3: out[o] = ybuf[4o]+ybuf[4o+1]+ybuf[4o+2]+ybuf[4o+3] ---
__global__ __launch_bounds__(256) void sum4_kernel(
    const float* __restrict__ ybuf,
    float* __restrict__ out)
{
    const int o = blockIdx.x >> 2;            // 0..255
    const int q = blockIdx.x & 3;             // d-quarter
    const int col = q * 1024 + 4 * threadIdx.x;
    const float* y0 = ybuf + (size_t)(4 * o) * D + col;
    float4v v0 = *(const float4v*)(y0);
    float4v v1 = *(const float4v*)(y0 + D);
    float4v v2 = *(const float4v*)(y0 + 2 * D);
    float4v v3 = *(const float4v*)(y0 + 3 * D);
    float4v s;
    #pragma unroll
    for (int k = 0; k < 4; ++k) s[k] = (v0[k] + v1[k]) + (v2[k] + v3[k]);
    *(float4v*)(out + (size_t)o * D + col) = s;
}

extern "C" void kernel_launch(void* const* d_in, const int* in_sizes, int n_in,
                              void* d_out, int out_size, void* d_ws, size_t ws_size,
                              hipStream_t stream) {
    const float* x    = (const float*)d_in[0];
    const float* A    = (const float*)d_in[1];
    const float* B    = (const float*)d_in[2];
    const int*   xids = (const int*)d_in[3];
    const int*   wids = (const int*)d_in[4];
    float*       out  = (float*)d_out;

    float* ybuf = (float*)d_ws;   // [1024][4096] f32 = 16 MB

    // K1 writes hpart into out rows 0..79; K2 reads it and writes out rows
    // 256+ and ybuf; K3 overwrites out rows 0..255 from ybuf. Stream-ordered.
    hipLaunchKernelGGL(h_kernel, dim3(NW * 4), dim3(256), 0, stream,
                       x, A, xids, wids, out);
    hipLaunchKernelGGL(y_kernel, dim3(NW * 4), dim3(256), 0, stream,
                       B, wids, ybuf, out);
    hipLaunchKernelGGL(sum4_kernel, dim3(NBL * 4), dim3(256), 0, stream,
                       ybuf, out);
}